// Round 11
// baseline (193.297 us; speedup 1.0000x reference)
//
#include <hip/hip_runtime.h>
#include <hip/hip_bf16.h>

#define BATCH 4
#define NSEQ  4096
#define CDIM  256
#define CQK   32
#define L2E   1.44269504088896340736f

typedef short bf16x8 __attribute__((ext_vector_type(8)));   // 8 bf16 in 4 VGPRs
typedef float f32x16 __attribute__((ext_vector_type(16)));
typedef unsigned short u16;
typedef unsigned int   u32;
typedef unsigned int   u32x4 __attribute__((ext_vector_type(4)));

__device__ __forceinline__ u32 pk2(float lo, float hi) {    // v_cvt_pk_bf16_f32
  u16 a = __builtin_bit_cast(u16, __float2bfloat16(lo));
  u16 b = __builtin_bit_cast(u16, __float2bfloat16(hi));
  return (u32)a | ((u32)b << 16);
}
__device__ __forceinline__ bf16x8 ld8(const u16* p) {
  uint4 u = *(const uint4*)p;
  return __builtin_bit_cast(bf16x8, u);
}
// raw v_exp_f32 via builtin (hazard-safe; inline-asm version failed r9 at absmax 2.69)
__device__ __forceinline__ float exp2_raw(float x) {
#if __has_builtin(__builtin_amdgcn_exp2f)
  return __builtin_amdgcn_exp2f(x);
#else
  return exp2f(x);
#endif
}

// ---------------- projection kernel: hT (bf16 [B][256][4096]), f,g (bf16 [B*N][32]) ------
// f is pre-scaled by log2(e) so attention can use exp2 directly.
__global__ __launch_bounds__(256) void proj_kernel(
    const float* __restrict__ x,
    const float* __restrict__ Wf, const float* __restrict__ bf,
    const float* __restrict__ Wg, const float* __restrict__ bg,
    const float* __restrict__ Wh, const float* __restrict__ bh,
    u16* __restrict__ f_ws, u16* __restrict__ g_ws, u16* __restrict__ hT_ws) {
  __shared__ float xs[16][260];                 // +4 pad: conflict-free strided reads
  const int tid  = threadIdx.x;
  const int row0 = blockIdx.x * 16;             // global row in [0,16384)

  { // stage 16 rows of x
    const int r = tid >> 4, j = tid & 15;
    const float4* xg = (const float4*)(x + ((size_t)row0 + r) * CDIM);
#pragma unroll
    for (int t = 0; t < 4; ++t)
      *(float4*)&xs[r][(j + t * 16) * 4] = xg[j + t * 16];
  }
  __syncthreads();

  { // f and g: thread (rr,c) does rows rr and rr+8, column c
    const int c = tid & 31, rr = tid >> 5;
    float af0 = bf[c], af1 = bf[c], ag0 = bg[c], ag1 = bg[c];
    for (int k = 0; k < CDIM; ++k) {
      float wf = Wf[k * CQK + c], wg = Wg[k * CQK + c];
      float x0 = xs[rr][k], x1 = xs[rr + 8][k];
      af0 = fmaf(x0, wf, af0); af1 = fmaf(x1, wf, af1);
      ag0 = fmaf(x0, wg, ag0); ag1 = fmaf(x1, wg, ag1);
    }
    f_ws[((size_t)row0 + rr)     * CQK + c] = (u16)(pk2(af0 * L2E, 0.f) & 0xFFFF);
    f_ws[((size_t)row0 + rr + 8) * CQK + c] = (u16)(pk2(af1 * L2E, 0.f) & 0xFFFF);
    g_ws[((size_t)row0 + rr)     * CQK + c] = (u16)(pk2(ag0, 0.f) & 0xFFFF);
    g_ws[((size_t)row0 + rr + 8) * CQK + c] = (u16)(pk2(ag1, 0.f) & 0xFFFF);
  }

  { // h: thread = output channel c; 16 rows; store transposed
    const int c = tid;
    float acc[16];
#pragma unroll
    for (int r = 0; r < 16; ++r) acc[r] = bh[c];
    for (int k = 0; k < CDIM; ++k) {
      float wk = Wh[k * CDIM + c];
#pragma unroll
      for (int r = 0; r < 16; ++r) acc[r] = fmaf(xs[r][k], wk, acc[r]);
    }
    const int b = row0 >> 12, n0 = row0 & (NSEQ - 1);
    u16* dst = hT_ws + ((size_t)b * CDIM + c) * NSEQ + n0;
    uint4 w0 = make_uint4(pk2(acc[0], acc[1]),  pk2(acc[2], acc[3]),
                          pk2(acc[4], acc[5]),  pk2(acc[6], acc[7]));
    uint4 w1 = make_uint4(pk2(acc[8], acc[9]),  pk2(acc[10], acc[11]),
                          pk2(acc[12], acc[13]), pk2(acc[14], acc[15]));
    *(uint4*)dst = w0;
    *(uint4*)(dst + 8) = w1;
  }
}

// ---------------- flash attention: key-split waves + rolling h register prefetch --------
// Block = 32 queries, 4 waves; wave w owns keys [w*1024,(w+1)*1024), computes ALL 256
// channels. h fragments for chunk it+1 are loaded into the SAME registers right after
// their chunk-it use (WAR-safe) -> each load has a full iteration to cover L2 latency.
// mfma_f32_32x32x16_bf16: A[row=l&31][k=(l>>5)*8+i], B[k=(l>>5)*8+i][col=l&31],
//   D[row=(r&3)+8*(r>>2)+4*(l>>5)][col=l&31]
__global__ __launch_bounds__(256, 2) void attn_kernel(
    const float* __restrict__ x, const float* __restrict__ gamma_p,
    const u16* __restrict__ f_ws, const u16* __restrict__ g_ws,
    const u16* __restrict__ hT_ws, float* __restrict__ out) {
  __shared__ u32   pls[4][64][64];              // 64KB partial-O exchange, lane-contiguous
  __shared__ float lsh[4][64];

  const int tid   = threadIdx.x;
  const int lan   = tid & 63;
  const int lan31 = lan & 31;
  const int g2    = lan >> 5;
  const int w     = tid >> 6;                   // wave id 0..3 (key-split)
  // XCD-aware swizzle: batch b pinned to XCDs {2b, 2b+1}
  const int bid   = blockIdx.x;
  const int xcd   = bid & 7;
  const int b     = xcd >> 1;
  const int n0    = (((xcd & 1) << 6) | (bid >> 3)) * 32;

  const float gamma = gamma_p[0];

  // query fragments (resident): B[k][n]=g[n][k]
  const u16* gp = g_ws + ((size_t)b * NSEQ + n0 + lan31) * CQK + g2 * 8;
  bf16x8 bg0 = ld8(gp);                         // k 0..15
  bf16x8 bg1 = ld8(gp + 16);                    // k 16..31

  f32x16 o[8], zfrag;
#pragma unroll
  for (int r = 0; r < 16; ++r) zfrag[r] = 0.f;
#pragma unroll
  for (int c = 0; c < 8; ++c) o[c] = zfrag;
  float l_run = 0.f;

  const u16* fbase = f_ws  + ((size_t)b * NSEQ + w * 1024 + lan31) * CQK + g2 * 8;
  const u16* hrow  = hT_ws + ((size_t)b * CDIM + lan31) * NSEQ + w * 1024 + g2 * 8;

  bf16x8 af0 = ld8(fbase), af1 = ld8(fbase + 16);
  const u16* fp = fbase + 32 * CQK;

  // prologue: h fragments for chunk 0 (16 x 16B = 64 VGPR, single rolling buffer)
  bf16x8 ha[8], hb[8];
#pragma unroll
  for (int cg = 0; cg < 8; ++cg) {
    ha[cg] = ld8(hrow + (size_t)(cg * 32) * NSEQ);
    hb[cg] = ld8(hrow + (size_t)(cg * 32) * NSEQ + 16);
  }

  for (int it = 0; it < 32; ++it) {
    // S^T = f . g^T : lane holds 16 key-scores (log2 domain) for query col n
    f32x16 s = __builtin_amdgcn_mfma_f32_32x32x16_bf16(af0, bg0, zfrag, 0, 0, 0);
    s        = __builtin_amdgcn_mfma_f32_32x32x16_bf16(af1, bg1, s,     0, 0, 0);

    // prefetch next f chunk (w=3 overrun lands in g_ws; in-bounds)
    bf16x8 naf0 = ld8(fp), naf1 = ld8(fp + 16);
    fp += 32 * CQK;

    // p = exp2(s), raw TRANS op via builtin
    float p[16];
#pragma unroll
    for (int r = 0; r < 16; ++r) p[r] = exp2_raw(s[r]);

    float t0 = (p[0] + p[1]) + (p[2] + p[3]);
    float t1 = (p[4] + p[5]) + (p[6] + p[7]);
    float t2 = (p[8] + p[9]) + (p[10] + p[11]);
    float t3 = (p[12] + p[13]) + (p[14] + p[15]);
    float rs = (t0 + t1) + (t2 + t3);
    auto rr = __builtin_amdgcn_permlane32_swap(__builtin_bit_cast(u32, rs),
                                               __builtin_bit_cast(u32, rs), false, false);
    l_run += __builtin_bit_cast(float, (u32)rr[0]) + __builtin_bit_cast(float, (u32)rr[1]);

    // pack P quads: quad q holds keys m = 8q + 4*g2 .. +3
    u32 q0a = pk2(p[0],  p[1]),  q0b = pk2(p[2],  p[3]);
    u32 q1a = pk2(p[4],  p[5]),  q1b = pk2(p[6],  p[7]);
    u32 q2a = pk2(p[8],  p[9]),  q2b = pk2(p[10], p[11]);
    u32 q3a = pk2(p[12], p[13]), q3b = pk2(p[14], p[15]);

    auto r02a = __builtin_amdgcn_permlane32_swap(q0a, q1a, false, false);
    auto r13a = __builtin_amdgcn_permlane32_swap(q0b, q1b, false, false);
    auto r02b = __builtin_amdgcn_permlane32_swap(q2a, q3a, false, false);
    auto r13b = __builtin_amdgcn_permlane32_swap(q2b, q3b, false, false);
    u32x4 apu0 = {(u32)r02a[0], (u32)r13a[0], (u32)r02a[1], (u32)r13a[1]};
    u32x4 apu1 = {(u32)r02b[0], (u32)r13b[0], (u32)r02b[1], (u32)r13b[1]};
    bf16x8 ap0 = __builtin_bit_cast(bf16x8, apu0);
    bf16x8 ap1 = __builtin_bit_cast(bf16x8, apu1);

    // O[cg] += P . h ; then roll-prefetch chunk it+1 into the same regs (WAR-safe).
    // Final-iteration overrun lands in f_ws/g_ws (in-bounds, values unused).
    const u16* hn = hrow + (it + 1) * 32;
#pragma unroll
    for (int cg = 0; cg < 8; ++cg) {
      o[cg] = __builtin_amdgcn_mfma_f32_32x32x16_bf16(ap0, ha[cg], o[cg], 0, 0, 0);
      o[cg] = __builtin_amdgcn_mfma_f32_32x32x16_bf16(ap1, hb[cg], o[cg], 0, 0, 0);
      ha[cg] = ld8(hn + (size_t)(cg * 32) * NSEQ);
      hb[cg] = ld8(hn + (size_t)(cg * 32) * NSEQ + 16);
    }

    af0 = naf0; af1 = naf1;
  }

  // ---- combine: all waves write bf16-packed partials; each wave sums one 64-ch slice ----
#pragma unroll
  for (int q = 0; q < 4; ++q)
#pragma unroll
    for (int r = 0; r < 16; ++r)
      pls[w][q * 16 + r][lan] = pk2(o[2 * q][r], o[2 * q + 1][r]);
  lsh[w][lan] = l_run;
  __syncthreads();

  float e0[16], e1[16];
#pragma unroll
  for (int r = 0; r < 16; ++r) { e0[r] = 0.f; e1[r] = 0.f; }
#pragma unroll
  for (int sgrp = 0; sgrp < 4; ++sgrp)
#pragma unroll
    for (int r = 0; r < 16; ++r) {
      u32 v = pls[sgrp][w * 16 + r][lan];
      e0[r] += __builtin_bit_cast(float, v << 16);
      e1[r] += __builtin_bit_cast(float, v & 0xFFFF0000u);
    }
  const float l_tot = lsh[0][lan] + lsh[1][lan] + lsh[2][lan] + lsh[3][lan];

  // epilogue: y = gamma * O / l + x ; wave w owns channels [w*64, w*64+64)
  const int cw = w * 64;
  const float gi = gamma / l_tot;
#pragma unroll
  for (int r = 0; r < 16; ++r) {
    const int nl = (r & 3) + 8 * (r >> 2) + 4 * g2;     // query row of this acc reg
    const float gir = __shfl(gi, nl);
    const size_t row = (size_t)b * NSEQ + n0 + nl;
    const size_t i0 = row * CDIM + cw + lan31;
    out[i0]      = fmaf(gir, e0[r], x[i0]);
    out[i0 + 32] = fmaf(gir, e1[r], x[i0 + 32]);
  }
}

extern "C" void kernel_launch(void* const* d_in, const int* in_sizes, int n_in,
                              void* d_out, int out_size, void* d_ws, size_t ws_size,
                              hipStream_t stream) {
  const float* x     = (const float*)d_in[0];
  const float* Wf    = (const float*)d_in[1];
  const float* bf    = (const float*)d_in[2];
  const float* Wg    = (const float*)d_in[3];
  const float* bg    = (const float*)d_in[4];
  const float* Wh    = (const float*)d_in[5];
  const float* bh    = (const float*)d_in[6];
  const float* gamma = (const float*)d_in[7];
  float* out = (float*)d_out;

  // layout: hT first so prefetch overruns land in f/g (in-bounds)
  u16* hT_ws = (u16*)d_ws;                                   // 8 MB
  u16* f_ws  = hT_ws + (size_t)BATCH * CDIM * NSEQ;          // 1 MB
  u16* g_ws  = f_ws  + (size_t)BATCH * NSEQ * CQK;           // 1 MB

  hipLaunchKernelGGL(proj_kernel, dim3(1024), dim3(256), 0, stream,
                     x, Wf, bf, Wg, bg, Wh, bh, f_ws, g_ws, hT_ws);
  hipLaunchKernelGGL(attn_kernel, dim3(512), dim3(256), 0, stream,
                     x, gamma, f_ws, g_ws, hT_ws, out);
}

// Round 12
// 136.357 us; speedup vs baseline: 1.4176x; 1.4176x over previous
//
#include <hip/hip_runtime.h>
#include <hip/hip_bf16.h>

#define BATCH 4
#define NSEQ  4096
#define CDIM  256
#define CQK   32
#define L2E   1.44269504088896340736f

typedef short bf16x8 __attribute__((ext_vector_type(8)));   // 8 bf16 in 4 VGPRs
typedef float f32x16 __attribute__((ext_vector_type(16)));
typedef unsigned short u16;
typedef unsigned int   u32;
typedef unsigned int   u32x4 __attribute__((ext_vector_type(4)));

__device__ __forceinline__ u32 pk2(float lo, float hi) {    // v_cvt_pk_bf16_f32
  u16 a = __builtin_bit_cast(u16, __float2bfloat16(lo));
  u16 b = __builtin_bit_cast(u16, __float2bfloat16(hi));
  return (u32)a | ((u32)b << 16);
}
__device__ __forceinline__ bf16x8 ld8(const u16* p) {
  uint4 u = *(const uint4*)p;
  return __builtin_bit_cast(bf16x8, u);
}
// raw v_exp_f32 via builtin (hazard-safe; inline-asm version failed r9 at absmax 2.69)
__device__ __forceinline__ float exp2_raw(float x) {
#if __has_builtin(__builtin_amdgcn_exp2f)
  return __builtin_amdgcn_exp2f(x);
#else
  return exp2f(x);
#endif
}

// ---------------- projection kernel: hT (bf16 [B][256][4096]), f,g (bf16 [B*N][32]) ------
// f is pre-scaled by log2(e) so attention can use exp2 directly.
__global__ __launch_bounds__(256) void proj_kernel(
    const float* __restrict__ x,
    const float* __restrict__ Wf, const float* __restrict__ bf,
    const float* __restrict__ Wg, const float* __restrict__ bg,
    const float* __restrict__ Wh, const float* __restrict__ bh,
    u16* __restrict__ f_ws, u16* __restrict__ g_ws, u16* __restrict__ hT_ws) {
  __shared__ float xs[16][260];                 // +4 pad: conflict-free strided reads
  const int tid  = threadIdx.x;
  const int row0 = blockIdx.x * 16;             // global row in [0,16384)

  { // stage 16 rows of x
    const int r = tid >> 4, j = tid & 15;
    const float4* xg = (const float4*)(x + ((size_t)row0 + r) * CDIM);
#pragma unroll
    for (int t = 0; t < 4; ++t)
      *(float4*)&xs[r][(j + t * 16) * 4] = xg[j + t * 16];
  }
  __syncthreads();

  { // f and g: thread (rr,c) does rows rr and rr+8, column c
    const int c = tid & 31, rr = tid >> 5;
    float af0 = bf[c], af1 = bf[c], ag0 = bg[c], ag1 = bg[c];
    for (int k = 0; k < CDIM; ++k) {
      float wf = Wf[k * CQK + c], wg = Wg[k * CQK + c];
      float x0 = xs[rr][k], x1 = xs[rr + 8][k];
      af0 = fmaf(x0, wf, af0); af1 = fmaf(x1, wf, af1);
      ag0 = fmaf(x0, wg, ag0); ag1 = fmaf(x1, wg, ag1);
    }
    f_ws[((size_t)row0 + rr)     * CQK + c] = (u16)(pk2(af0 * L2E, 0.f) & 0xFFFF);
    f_ws[((size_t)row0 + rr + 8) * CQK + c] = (u16)(pk2(af1 * L2E, 0.f) & 0xFFFF);
    g_ws[((size_t)row0 + rr)     * CQK + c] = (u16)(pk2(ag0, 0.f) & 0xFFFF);
    g_ws[((size_t)row0 + rr + 8) * CQK + c] = (u16)(pk2(ag1, 0.f) & 0xFFFF);
  }

  { // h: thread = output channel c; 16 rows; store transposed
    const int c = tid;
    float acc[16];
#pragma unroll
    for (int r = 0; r < 16; ++r) acc[r] = bh[c];
    for (int k = 0; k < CDIM; ++k) {
      float wk = Wh[k * CDIM + c];
#pragma unroll
      for (int r = 0; r < 16; ++r) acc[r] = fmaf(xs[r][k], wk, acc[r]);
    }
    const int b = row0 >> 12, n0 = row0 & (NSEQ - 1);
    u16* dst = hT_ws + ((size_t)b * CDIM + c) * NSEQ + n0;
    uint4 w0 = make_uint4(pk2(acc[0], acc[1]),  pk2(acc[2], acc[3]),
                          pk2(acc[4], acc[5]),  pk2(acc[6], acc[7]));
    uint4 w1 = make_uint4(pk2(acc[8], acc[9]),  pk2(acc[10], acc[11]),
                          pk2(acc[12], acc[13]), pk2(acc[14], acc[15]));
    *(uint4*)dst = w0;
    *(uint4*)(dst + 8) = w1;
  }
}

// ---------------- flash attention: 64-query blocks, 8 waves = 4 key-splits x 2 ch-halves -
// Wave (kw,ch): keys [kw*1024,+1024), channels [ch*128,+128), BOTH 32-query halves.
// One h load feeds 4 MFMAs (2 query halves x 2 k-steps) -> line-touches per query halved.
// mfma_f32_32x32x16_bf16: A[row=l&31][k=(l>>5)*8+i], B[k=(l>>5)*8+i][col=l&31],
//   D[row=(r&3)+8*(r>>2)+4*(l>>5)][col=l&31]
__global__ __launch_bounds__(512, 2) void attn_kernel(
    const float* __restrict__ x, const float* __restrict__ gamma_p,
    const u16* __restrict__ f_ws, const u16* __restrict__ g_ws,
    const u16* __restrict__ hT_ws, float* __restrict__ out) {
  __shared__ u32   pls[4][64][64];              // 64KB partial-O exchange (2 rounds)
  __shared__ float lsh[4][2][64];

  const int tid   = threadIdx.x;
  const int lan   = tid & 63;
  const int lan31 = lan & 31;
  const int g2    = lan >> 5;
  const int w     = tid >> 6;                   // wave id 0..7
  const int kw    = w & 3;                      // key split 0..3
  const int ch    = w >> 2;                     // channel half 0/1
  // XCD-aware swizzle: batch b pinned to XCDs {2b, 2b+1}; 32 blocks/batch
  const int bid   = blockIdx.x;
  const int xcd   = bid & 7;
  const int b     = xcd >> 1;
  const int n0    = ((((xcd & 1) << 5) | (bid >> 3))) * 64;

  const float gamma = gamma_p[0];

  // query fragments, both 32-query halves: B[k][n]=g[n][k]
  const u16* gp0 = g_ws + ((size_t)b * NSEQ + n0 + lan31) * CQK + g2 * 8;
  const u16* gp1 = gp0 + 32 * CQK;
  bf16x8 bgA0 = ld8(gp0), bgA1 = ld8(gp0 + 16);
  bf16x8 bgB0 = ld8(gp1), bgB1 = ld8(gp1 + 16);

  f32x16 o[4][2], zfrag;                        // [cg][qhalf] : 128 acc regs
#pragma unroll
  for (int r = 0; r < 16; ++r) zfrag[r] = 0.f;
#pragma unroll
  for (int c = 0; c < 4; ++c) { o[c][0] = zfrag; o[c][1] = zfrag; }
  float l0 = 0.f, l1 = 0.f;

  const u16* fbase = f_ws  + ((size_t)b * NSEQ + kw * 1024 + lan31) * CQK + g2 * 8;
  const u16* hbase = hT_ws + ((size_t)b * CDIM + ch * 128 + lan31) * NSEQ + kw * 1024 + g2 * 8;

  bf16x8 af0 = ld8(fbase), af1 = ld8(fbase + 16);
  const u16* fp = fbase + 32 * CQK;

  for (int it = 0; it < 32; ++it) {
    // S^T for both query halves (shared f)
    f32x16 sA = __builtin_amdgcn_mfma_f32_32x32x16_bf16(af0, bgA0, zfrag, 0, 0, 0);
    sA        = __builtin_amdgcn_mfma_f32_32x32x16_bf16(af1, bgA1, sA,    0, 0, 0);
    f32x16 sB = __builtin_amdgcn_mfma_f32_32x32x16_bf16(af0, bgB0, zfrag, 0, 0, 0);
    sB        = __builtin_amdgcn_mfma_f32_32x32x16_bf16(af1, bgB1, sB,    0, 0, 0);

    bf16x8 naf0 = ld8(fp), naf1 = ld8(fp + 16);   // f prefetch (overrun in-bounds)
    fp += 32 * CQK;

    // ---- query half A: exp2, row-sum, pack, A-frags ----
    bf16x8 apA0, apA1;
    {
      float p[16];
#pragma unroll
      for (int r = 0; r < 16; ++r) p[r] = exp2_raw(sA[r]);
      float rs = ((p[0]+p[1])+(p[2]+p[3])) + ((p[4]+p[5])+(p[6]+p[7]))
               + ((p[8]+p[9])+(p[10]+p[11])) + ((p[12]+p[13])+(p[14]+p[15]));
      auto rr = __builtin_amdgcn_permlane32_swap(__builtin_bit_cast(u32, rs),
                                                 __builtin_bit_cast(u32, rs), false, false);
      l0 += __builtin_bit_cast(float, (u32)rr[0]) + __builtin_bit_cast(float, (u32)rr[1]);
      u32 q0a = pk2(p[0],p[1]),   q0b = pk2(p[2],p[3]);
      u32 q1a = pk2(p[4],p[5]),   q1b = pk2(p[6],p[7]);
      u32 q2a = pk2(p[8],p[9]),   q2b = pk2(p[10],p[11]);
      u32 q3a = pk2(p[12],p[13]), q3b = pk2(p[14],p[15]);
      auto r02a = __builtin_amdgcn_permlane32_swap(q0a, q1a, false, false);
      auto r13a = __builtin_amdgcn_permlane32_swap(q0b, q1b, false, false);
      auto r02b = __builtin_amdgcn_permlane32_swap(q2a, q3a, false, false);
      auto r13b = __builtin_amdgcn_permlane32_swap(q2b, q3b, false, false);
      u32x4 u0 = {(u32)r02a[0], (u32)r13a[0], (u32)r02a[1], (u32)r13a[1]};
      u32x4 u1 = {(u32)r02b[0], (u32)r13b[0], (u32)r02b[1], (u32)r13b[1]};
      apA0 = __builtin_bit_cast(bf16x8, u0);
      apA1 = __builtin_bit_cast(bf16x8, u1);
    }
    // ---- query half B ----
    bf16x8 apB0, apB1;
    {
      float p[16];
#pragma unroll
      for (int r = 0; r < 16; ++r) p[r] = exp2_raw(sB[r]);
      float rs = ((p[0]+p[1])+(p[2]+p[3])) + ((p[4]+p[5])+(p[6]+p[7]))
               + ((p[8]+p[9])+(p[10]+p[11])) + ((p[12]+p[13])+(p[14]+p[15]));
      auto rr = __builtin_amdgcn_permlane32_swap(__builtin_bit_cast(u32, rs),
                                                 __builtin_bit_cast(u32, rs), false, false);
      l1 += __builtin_bit_cast(float, (u32)rr[0]) + __builtin_bit_cast(float, (u32)rr[1]);
      u32 q0a = pk2(p[0],p[1]),   q0b = pk2(p[2],p[3]);
      u32 q1a = pk2(p[4],p[5]),   q1b = pk2(p[6],p[7]);
      u32 q2a = pk2(p[8],p[9]),   q2b = pk2(p[10],p[11]);
      u32 q3a = pk2(p[12],p[13]), q3b = pk2(p[14],p[15]);
      auto r02a = __builtin_amdgcn_permlane32_swap(q0a, q1a, false, false);
      auto r13a = __builtin_amdgcn_permlane32_swap(q0b, q1b, false, false);
      auto r02b = __builtin_amdgcn_permlane32_swap(q2a, q3a, false, false);
      auto r13b = __builtin_amdgcn_permlane32_swap(q2b, q3b, false, false);
      u32x4 u0 = {(u32)r02a[0], (u32)r13a[0], (u32)r02a[1], (u32)r13a[1]};
      u32x4 u1 = {(u32)r02b[0], (u32)r13b[0], (u32)r02b[1], (u32)r13b[1]};
      apB0 = __builtin_bit_cast(bf16x8, u0);
      apB1 = __builtin_bit_cast(bf16x8, u1);
    }

    // PV: one h load feeds 4 MFMAs (both query halves)
    const u16* hp = hbase + it * 32;
#pragma unroll
    for (int cg = 0; cg < 4; ++cg) {
      bf16x8 ha = ld8(hp + (size_t)(cg * 32) * NSEQ);
      bf16x8 hb = ld8(hp + (size_t)(cg * 32) * NSEQ + 16);
      o[cg][0] = __builtin_amdgcn_mfma_f32_32x32x16_bf16(apA0, ha, o[cg][0], 0, 0, 0);
      o[cg][0] = __builtin_amdgcn_mfma_f32_32x32x16_bf16(apA1, hb, o[cg][0], 0, 0, 0);
      o[cg][1] = __builtin_amdgcn_mfma_f32_32x32x16_bf16(apB0, ha, o[cg][1], 0, 0, 0);
      o[cg][1] = __builtin_amdgcn_mfma_f32_32x32x16_bf16(apB1, hb, o[cg][1], 0, 0, 0);
    }

    af0 = naf0; af1 = naf1;
  }

  // l partials: identical across ch halves -> only ch=0 writes
  if (ch == 0) { lsh[kw][0][lan] = l0; lsh[kw][1][lan] = l1; }

  // ---- two combine rounds (one per channel half), r10-style 4-way add ----
#pragma unroll
  for (int round = 0; round < 2; ++round) {
    __syncthreads();
    if (ch == round) {
#pragma unroll
      for (int qh = 0; qh < 2; ++qh)
#pragma unroll
        for (int pc = 0; pc < 2; ++pc)
#pragma unroll
          for (int r = 0; r < 16; ++r)
            pls[kw][(qh * 2 + pc) * 16 + r][lan] = pk2(o[pc * 2][qh][r], o[pc * 2 + 1][qh][r]);
    }
    __syncthreads();
    if (ch == round) {
      const int qh = kw >> 1, pc = kw & 1;      // this wave's output slice
      float e0[16], e1[16];
#pragma unroll
      for (int r = 0; r < 16; ++r) { e0[r] = 0.f; e1[r] = 0.f; }
#pragma unroll
      for (int kk = 0; kk < 4; ++kk)
#pragma unroll
        for (int r = 0; r < 16; ++r) {
          u32 v = pls[kk][kw * 16 + r][lan];
          e0[r] += __builtin_bit_cast(float, v << 16);
          e1[r] += __builtin_bit_cast(float, v & 0xFFFF0000u);
        }
      const float l_tot = lsh[0][qh][lan] + lsh[1][qh][lan] + lsh[2][qh][lan] + lsh[3][qh][lan];
      const float gi = gamma / l_tot;
#pragma unroll
      for (int r = 0; r < 16; ++r) {
        const int nl = (r & 3) + 8 * (r >> 2) + 4 * g2;   // query row within half
        const float gir = __shfl(gi, nl);
        const size_t row = (size_t)b * NSEQ + n0 + qh * 32 + nl;
        const size_t i0 = row * CDIM + round * 128 + pc * 64 + lan31;
        out[i0]      = fmaf(gir, e0[r], x[i0]);
        out[i0 + 32] = fmaf(gir, e1[r], x[i0 + 32]);
      }
    }
  }
}

extern "C" void kernel_launch(void* const* d_in, const int* in_sizes, int n_in,
                              void* d_out, int out_size, void* d_ws, size_t ws_size,
                              hipStream_t stream) {
  const float* x     = (const float*)d_in[0];
  const float* Wf    = (const float*)d_in[1];
  const float* bf    = (const float*)d_in[2];
  const float* Wg    = (const float*)d_in[3];
  const float* bg    = (const float*)d_in[4];
  const float* Wh    = (const float*)d_in[5];
  const float* bh    = (const float*)d_in[6];
  const float* gamma = (const float*)d_in[7];
  float* out = (float*)d_out;

  // layout: hT first so prefetch overruns land in f/g (in-bounds)
  u16* hT_ws = (u16*)d_ws;                                   // 8 MB
  u16* f_ws  = hT_ws + (size_t)BATCH * CDIM * NSEQ;          // 1 MB
  u16* g_ws  = f_ws  + (size_t)BATCH * NSEQ * CQK;           // 1 MB

  hipLaunchKernelGGL(proj_kernel, dim3(1024), dim3(256), 0, stream,
                     x, Wf, bf, Wg, bg, Wh, bh, f_ws, g_ws, hT_ws);
  hipLaunchKernelGGL(attn_kernel, dim3(256), dim3(512), 0, stream,
                     x, gamma, f_ws, g_ws, hT_ws, out);
}

// Round 13
// 135.377 us; speedup vs baseline: 1.4278x; 1.0072x over previous
//
#include <hip/hip_runtime.h>
#include <hip/hip_bf16.h>

#define BATCH 4
#define NSEQ  4096
#define CDIM  256
#define CQK   32
#define L2E   1.44269504088896340736f

typedef short bf16x8 __attribute__((ext_vector_type(8)));   // 8 bf16 in 4 VGPRs
typedef float f32x16 __attribute__((ext_vector_type(16)));
typedef unsigned short u16;
typedef unsigned int   u32;
typedef unsigned int   u32x4 __attribute__((ext_vector_type(4)));

__device__ __forceinline__ u32 pk2(float lo, float hi) {    // v_cvt_pk_bf16_f32
  u16 a = __builtin_bit_cast(u16, __float2bfloat16(lo));
  u16 b = __builtin_bit_cast(u16, __float2bfloat16(hi));
  return (u32)a | ((u32)b << 16);
}
__device__ __forceinline__ bf16x8 ld8(const u16* p) {
  uint4 u = *(const uint4*)p;
  return __builtin_bit_cast(bf16x8, u);
}
// raw v_exp_f32 via builtin (hazard-safe; inline-asm version failed r9 at absmax 2.69)
__device__ __forceinline__ float exp2_raw(float x) {
#if __has_builtin(__builtin_amdgcn_exp2f)
  return __builtin_amdgcn_exp2f(x);
#else
  return exp2f(x);
#endif
}

// ---------------- projection kernel: hT (bf16 [B][256][4096]), f,g (bf16 [B*N][32]) ------
// f is pre-scaled by log2(e) so attention can use exp2 directly.
__global__ __launch_bounds__(256) void proj_kernel(
    const float* __restrict__ x,
    const float* __restrict__ Wf, const float* __restrict__ bf,
    const float* __restrict__ Wg, const float* __restrict__ bg,
    const float* __restrict__ Wh, const float* __restrict__ bh,
    u16* __restrict__ f_ws, u16* __restrict__ g_ws, u16* __restrict__ hT_ws) {
  __shared__ float xs[16][260];                 // +4 pad: conflict-free strided reads
  const int tid  = threadIdx.x;
  const int row0 = blockIdx.x * 16;             // global row in [0,16384)

  { // stage 16 rows of x
    const int r = tid >> 4, j = tid & 15;
    const float4* xg = (const float4*)(x + ((size_t)row0 + r) * CDIM);
#pragma unroll
    for (int t = 0; t < 4; ++t)
      *(float4*)&xs[r][(j + t * 16) * 4] = xg[j + t * 16];
  }
  __syncthreads();

  { // f and g: thread (rr,c) does rows rr and rr+8, column c
    const int c = tid & 31, rr = tid >> 5;
    float af0 = bf[c], af1 = bf[c], ag0 = bg[c], ag1 = bg[c];
    for (int k = 0; k < CDIM; ++k) {
      float wf = Wf[k * CQK + c], wg = Wg[k * CQK + c];
      float x0 = xs[rr][k], x1 = xs[rr + 8][k];
      af0 = fmaf(x0, wf, af0); af1 = fmaf(x1, wf, af1);
      ag0 = fmaf(x0, wg, ag0); ag1 = fmaf(x1, wg, ag1);
    }
    f_ws[((size_t)row0 + rr)     * CQK + c] = (u16)(pk2(af0 * L2E, 0.f) & 0xFFFF);
    f_ws[((size_t)row0 + rr + 8) * CQK + c] = (u16)(pk2(af1 * L2E, 0.f) & 0xFFFF);
    g_ws[((size_t)row0 + rr)     * CQK + c] = (u16)(pk2(ag0, 0.f) & 0xFFFF);
    g_ws[((size_t)row0 + rr + 8) * CQK + c] = (u16)(pk2(ag1, 0.f) & 0xFFFF);
  }

  { // h: thread = output channel c; 16 rows; store transposed
    const int c = tid;
    float acc[16];
#pragma unroll
    for (int r = 0; r < 16; ++r) acc[r] = bh[c];
    for (int k = 0; k < CDIM; ++k) {
      float wk = Wh[k * CDIM + c];
#pragma unroll
      for (int r = 0; r < 16; ++r) acc[r] = fmaf(xs[r][k], wk, acc[r]);
    }
    const int b = row0 >> 12, n0 = row0 & (NSEQ - 1);
    u16* dst = hT_ws + ((size_t)b * CDIM + c) * NSEQ + n0;
    uint4 w0 = make_uint4(pk2(acc[0], acc[1]),  pk2(acc[2], acc[3]),
                          pk2(acc[4], acc[5]),  pk2(acc[6], acc[7]));
    uint4 w1 = make_uint4(pk2(acc[8], acc[9]),  pk2(acc[10], acc[11]),
                          pk2(acc[12], acc[13]), pk2(acc[14], acc[15]));
    *(uint4*)dst = w0;
    *(uint4*)(dst + 8) = w1;
  }
}

// ---------------- flash attention: 128-query tiles x 2 channel-blocks -------------------
// Grid 256 = 32 q-tiles/batch x 2 ch-blocks. Block = 8 waves = 4 key-splits x 2 ch-qtrs.
// Wave: 128 q x 64 ch x 1024 keys; one h load feeds 8 MFMAs (4 query tiles x 2 k-steps).
// mfma_f32_32x32x16_bf16: A[row=l&31][k=(l>>5)*8+i], B[k=(l>>5)*8+i][col=l&31],
//   D[row=(r&3)+8*(r>>2)+4*(l>>5)][col=l&31]
__global__ __launch_bounds__(512, 2) void attn_kernel(
    const float* __restrict__ x, const float* __restrict__ gamma_p,
    const u16* __restrict__ f_ws, const u16* __restrict__ g_ws,
    const u16* __restrict__ hT_ws, float* __restrict__ out) {
  __shared__ u32   pls[4][2][2][16][64];        // [kw][cq][qhl][r][lane] 64KB (2 rounds)
  __shared__ float lsh[4][4][64];               // [kw][qh][lane] 4KB

  const int tid   = threadIdx.x;
  const int lan   = tid & 63;
  const int lan31 = lan & 31;
  const int g2    = lan >> 5;
  const int w     = tid >> 6;                   // wave id 0..7
  const int kw    = w & 3;                      // key split 0..3
  const int cq    = w >> 2;                     // channel quarter within block: 0/1
  // XCD-aware: batch b pinned to XCDs {2b,2b+1}; decode (q-tile, ch-block)
  const int bid   = blockIdx.x;
  const int xcd   = bid & 7;
  const int b     = xcd >> 1;
  const int inner = bid >> 3;                   // 0..31
  const int cb    = inner & 1;                  // channel block 0/1 (128 ch)
  const int n0    = (((xcd & 1) << 4) | (inner >> 1)) * 128;

  const float gamma = gamma_p[0];

  // query fragments for 4 query tiles: B[k][n]=g[n][k]
  bf16x8 bg[4][2];
#pragma unroll
  for (int qh = 0; qh < 4; ++qh) {
    const u16* gp = g_ws + ((size_t)b * NSEQ + n0 + qh * 32 + lan31) * CQK + g2 * 8;
    bg[qh][0] = ld8(gp);
    bg[qh][1] = ld8(gp + 16);
  }

  f32x16 o[2][4], zfrag;                        // [cg][qh] = 128 acc VGPRs
#pragma unroll
  for (int r = 0; r < 16; ++r) zfrag[r] = 0.f;
#pragma unroll
  for (int cg = 0; cg < 2; ++cg)
#pragma unroll
    for (int qh = 0; qh < 4; ++qh) o[cg][qh] = zfrag;
  float l[4] = {0.f, 0.f, 0.f, 0.f};

  const u16* fbase = f_ws + ((size_t)b * NSEQ + kw * 1024 + lan31) * CQK + g2 * 8;
  const u16* hbase = hT_ws + ((size_t)b * CDIM + cb * 128 + cq * 64 + lan31) * NSEQ
                   + kw * 1024 + g2 * 8;

  bf16x8 af0 = ld8(fbase), af1 = ld8(fbase + 16);
  const u16* fp = fbase + 32 * CQK;

  for (int it = 0; it < 32; ++it) {
    bf16x8 naf0 = ld8(fp), naf1 = ld8(fp + 16);   // f prefetch (overrun in-bounds)
    fp += 32 * CQK;
    const u16* hp = hbase + it * 32;
    bf16x8 ha0 = ld8(hp);
    bf16x8 hb0 = ld8(hp + 16);
    bf16x8 ha1 = ld8(hp + (size_t)32 * NSEQ);
    bf16x8 hb1 = ld8(hp + (size_t)32 * NSEQ + 16);

#pragma unroll
    for (int qh = 0; qh < 4; ++qh) {
      f32x16 s = __builtin_amdgcn_mfma_f32_32x32x16_bf16(af0, bg[qh][0], zfrag, 0, 0, 0);
      s        = __builtin_amdgcn_mfma_f32_32x32x16_bf16(af1, bg[qh][1], s,     0, 0, 0);

      float p[16];
#pragma unroll
      for (int r = 0; r < 16; ++r) p[r] = exp2_raw(s[r]);
      float rs = ((p[0]+p[1])+(p[2]+p[3])) + ((p[4]+p[5])+(p[6]+p[7]))
               + ((p[8]+p[9])+(p[10]+p[11])) + ((p[12]+p[13])+(p[14]+p[15]));
      auto rr = __builtin_amdgcn_permlane32_swap(__builtin_bit_cast(u32, rs),
                                                 __builtin_bit_cast(u32, rs), false, false);
      l[qh] += __builtin_bit_cast(float, (u32)rr[0]) + __builtin_bit_cast(float, (u32)rr[1]);

      u32 q0a = pk2(p[0],p[1]),   q0b = pk2(p[2],p[3]);
      u32 q1a = pk2(p[4],p[5]),   q1b = pk2(p[6],p[7]);
      u32 q2a = pk2(p[8],p[9]),   q2b = pk2(p[10],p[11]);
      u32 q3a = pk2(p[12],p[13]), q3b = pk2(p[14],p[15]);
      auto r02a = __builtin_amdgcn_permlane32_swap(q0a, q1a, false, false);
      auto r13a = __builtin_amdgcn_permlane32_swap(q0b, q1b, false, false);
      auto r02b = __builtin_amdgcn_permlane32_swap(q2a, q3a, false, false);
      auto r13b = __builtin_amdgcn_permlane32_swap(q2b, q3b, false, false);
      u32x4 u0 = {(u32)r02a[0], (u32)r13a[0], (u32)r02a[1], (u32)r13a[1]};
      u32x4 u1 = {(u32)r02b[0], (u32)r13b[0], (u32)r02b[1], (u32)r13b[1]};
      bf16x8 ap0 = __builtin_bit_cast(bf16x8, u0);
      bf16x8 ap1 = __builtin_bit_cast(bf16x8, u1);

      o[0][qh] = __builtin_amdgcn_mfma_f32_32x32x16_bf16(ap0, ha0, o[0][qh], 0, 0, 0);
      o[0][qh] = __builtin_amdgcn_mfma_f32_32x32x16_bf16(ap1, hb0, o[0][qh], 0, 0, 0);
      o[1][qh] = __builtin_amdgcn_mfma_f32_32x32x16_bf16(ap0, ha1, o[1][qh], 0, 0, 0);
      o[1][qh] = __builtin_amdgcn_mfma_f32_32x32x16_bf16(ap1, hb1, o[1][qh], 0, 0, 0);
    }

    af0 = naf0; af1 = naf1;
  }

  // ---- combine: 2 rounds (query-tile pairs); 4-way key-split sum via LDS ----
#pragma unroll
  for (int round = 0; round < 2; ++round) {
    __syncthreads();
    {
#pragma unroll
      for (int qhl = 0; qhl < 2; ++qhl)
#pragma unroll
        for (int r = 0; r < 16; ++r)
          pls[kw][cq][qhl][r][lan] = pk2(o[0][round * 2 + qhl][r], o[1][round * 2 + qhl][r]);
      if (round == 0 && cq == 0) {
        lsh[kw][0][lan] = l[0]; lsh[kw][1][lan] = l[1];
        lsh[kw][2][lan] = l[2]; lsh[kw][3][lan] = l[3];
      }
    }
    __syncthreads();
    {
      const int qhl = kw & 1, rb = (kw >> 1) * 8;
      const int qh  = round * 2 + qhl;
      float e0[8], e1[8];
#pragma unroll
      for (int j = 0; j < 8; ++j) { e0[j] = 0.f; e1[j] = 0.f; }
#pragma unroll
      for (int kk = 0; kk < 4; ++kk)
#pragma unroll
        for (int j = 0; j < 8; ++j) {
          u32 v = pls[kk][cq][qhl][rb + j][lan];
          e0[j] += __builtin_bit_cast(float, v << 16);
          e1[j] += __builtin_bit_cast(float, v & 0xFFFF0000u);
        }
      const float l_tot = lsh[0][qh][lan] + lsh[1][qh][lan]
                        + lsh[2][qh][lan] + lsh[3][qh][lan];
      const float gi = gamma / l_tot;
#pragma unroll
      for (int j = 0; j < 8; ++j) {
        const int r  = rb + j;
        const int nl = (r & 3) + 8 * (r >> 2) + 4 * g2;   // query row within 32-tile
        const float gir = __shfl(gi, nl);
        const size_t row = (size_t)b * NSEQ + n0 + qh * 32 + nl;
        const size_t i0 = row * CDIM + cb * 128 + cq * 64 + lan31;
        out[i0]      = fmaf(gir, e0[j], x[i0]);
        out[i0 + 32] = fmaf(gir, e1[j], x[i0 + 32]);
      }
    }
  }
}

extern "C" void kernel_launch(void* const* d_in, const int* in_sizes, int n_in,
                              void* d_out, int out_size, void* d_ws, size_t ws_size,
                              hipStream_t stream) {
  const float* x     = (const float*)d_in[0];
  const float* Wf    = (const float*)d_in[1];
  const float* bf    = (const float*)d_in[2];
  const float* Wg    = (const float*)d_in[3];
  const float* bg    = (const float*)d_in[4];
  const float* Wh    = (const float*)d_in[5];
  const float* bh    = (const float*)d_in[6];
  const float* gamma = (const float*)d_in[7];
  float* out = (float*)d_out;

  // layout: hT first so prefetch overruns land in f/g (in-bounds)
  u16* hT_ws = (u16*)d_ws;                                   // 8 MB
  u16* f_ws  = hT_ws + (size_t)BATCH * CDIM * NSEQ;          // 1 MB
  u16* g_ws  = f_ws  + (size_t)BATCH * NSEQ * CQK;           // 1 MB

  hipLaunchKernelGGL(proj_kernel, dim3(1024), dim3(256), 0, stream,
                     x, Wf, bf, Wg, bg, Wh, bh, f_ws, g_ws, hT_ws);
  hipLaunchKernelGGL(attn_kernel, dim3(256), dim3(512), 0, stream,
                     x, gamma, f_ws, g_ws, hT_ws, out);
}

// Round 14
// 119.320 us; speedup vs baseline: 1.6200x; 1.1346x over previous
//
#include <hip/hip_runtime.h>
#include <hip/hip_bf16.h>

#define BATCH 4
#define NSEQ  4096
#define CDIM  256
#define CQK   32
#define L2E   1.44269504088896340736f

typedef short bf16x8 __attribute__((ext_vector_type(8)));   // 8 bf16 in 4 VGPRs
typedef float f32x16 __attribute__((ext_vector_type(16)));
typedef unsigned short u16;
typedef unsigned int   u32;
typedef unsigned int   u32x4 __attribute__((ext_vector_type(4)));

__device__ __forceinline__ u32 pk2(float lo, float hi) {    // v_cvt_pk_bf16_f32
  u16 a = __builtin_bit_cast(u16, __float2bfloat16(lo));
  u16 b = __builtin_bit_cast(u16, __float2bfloat16(hi));
  return (u32)a | ((u32)b << 16);
}
__device__ __forceinline__ bf16x8 ld8(const u16* p) {
  uint4 u = *(const uint4*)p;
  return __builtin_bit_cast(bf16x8, u);
}
// raw v_exp_f32 via builtin (hazard-safe; inline-asm version failed r9 at absmax 2.69)
__device__ __forceinline__ float exp2_raw(float x) {
#if __has_builtin(__builtin_amdgcn_exp2f)
  return __builtin_amdgcn_exp2f(x);
#else
  return exp2f(x);
#endif
}

// ---------------- projection kernel: hT (bf16 [B][256][4096]), f,g (bf16 [B*N][32]) ------
// f is pre-scaled by log2(e) so attention can use exp2 directly.
__global__ __launch_bounds__(256) void proj_kernel(
    const float* __restrict__ x,
    const float* __restrict__ Wf, const float* __restrict__ bf,
    const float* __restrict__ Wg, const float* __restrict__ bg,
    const float* __restrict__ Wh, const float* __restrict__ bh,
    u16* __restrict__ f_ws, u16* __restrict__ g_ws, u16* __restrict__ hT_ws) {
  __shared__ float xs[16][260];                 // +4 pad: conflict-free strided reads
  const int tid  = threadIdx.x;
  const int row0 = blockIdx.x * 16;             // global row in [0,16384)

  { // stage 16 rows of x
    const int r = tid >> 4, j = tid & 15;
    const float4* xg = (const float4*)(x + ((size_t)row0 + r) * CDIM);
#pragma unroll
    for (int t = 0; t < 4; ++t)
      *(float4*)&xs[r][(j + t * 16) * 4] = xg[j + t * 16];
  }
  __syncthreads();

  { // f and g: thread (rr,c) does rows rr and rr+8, column c
    const int c = tid & 31, rr = tid >> 5;
    float af0 = bf[c], af1 = bf[c], ag0 = bg[c], ag1 = bg[c];
    for (int k = 0; k < CDIM; ++k) {
      float wf = Wf[k * CQK + c], wg = Wg[k * CQK + c];
      float x0 = xs[rr][k], x1 = xs[rr + 8][k];
      af0 = fmaf(x0, wf, af0); af1 = fmaf(x1, wf, af1);
      ag0 = fmaf(x0, wg, ag0); ag1 = fmaf(x1, wg, ag1);
    }
    f_ws[((size_t)row0 + rr)     * CQK + c] = (u16)(pk2(af0 * L2E, 0.f) & 0xFFFF);
    f_ws[((size_t)row0 + rr + 8) * CQK + c] = (u16)(pk2(af1 * L2E, 0.f) & 0xFFFF);
    g_ws[((size_t)row0 + rr)     * CQK + c] = (u16)(pk2(ag0, 0.f) & 0xFFFF);
    g_ws[((size_t)row0 + rr + 8) * CQK + c] = (u16)(pk2(ag1, 0.f) & 0xFFFF);
  }

  { // h: thread = output channel c; 16 rows; store transposed
    const int c = tid;
    float acc[16];
#pragma unroll
    for (int r = 0; r < 16; ++r) acc[r] = bh[c];
    for (int k = 0; k < CDIM; ++k) {
      float wk = Wh[k * CDIM + c];
#pragma unroll
      for (int r = 0; r < 16; ++r) acc[r] = fmaf(xs[r][k], wk, acc[r]);
    }
    const int b = row0 >> 12, n0 = row0 & (NSEQ - 1);
    u16* dst = hT_ws + ((size_t)b * CDIM + c) * NSEQ + n0;
    uint4 w0 = make_uint4(pk2(acc[0], acc[1]),  pk2(acc[2], acc[3]),
                          pk2(acc[4], acc[5]),  pk2(acc[6], acc[7]));
    uint4 w1 = make_uint4(pk2(acc[8], acc[9]),  pk2(acc[10], acc[11]),
                          pk2(acc[12], acc[13]), pk2(acc[14], acc[15]));
    *(uint4*)dst = w0;
    *(uint4*)(dst + 8) = w1;
  }
}

// ---------------- flash attention: 128q tiles, LDS P-exchange kills softmax dup ---------
// Grid 256 = 32 q-tiles/batch x 2 ch-blocks. Block = 8 waves = 4 key-splits x 2 cq.
// Wave (kw,cq): computes QK+softmax+pack for query tiles {cq*2, cq*2+1} ONLY, exchanges
// packed A-frags via double-buffered LDS (1 barrier/iter), PVs all 4 q-tiles on its own
// 64 channels. Softmax/QK redundancy: 4x -> 2x (only cb remains). h loads issued before
// the barrier double as prefetch.
// mfma_f32_32x32x16_bf16: A[row=l&31][k=(l>>5)*8+i], B[k=(l>>5)*8+i][col=l&31],
//   D[row=(r&3)+8*(r>>2)+4*(l>>5)][col=l&31]
__global__ __launch_bounds__(512, 2) void attn_kernel(
    const float* __restrict__ x, const float* __restrict__ gamma_p,
    const u16* __restrict__ f_ws, const u16* __restrict__ g_ws,
    const u16* __restrict__ hT_ws, float* __restrict__ out) {
  __shared__ u32x4 xb[2][4][4][2][64];          // [buf][kw][qh][fr][lane] 64KB P-exchange
  __shared__ u32   pls[4][2][2][16][64];        // [kw][cq][qhl][r][lane] 64KB combine
  __shared__ float lsh[4][4][64];               // [kw][qh][lane] 4KB

  const int tid   = threadIdx.x;
  const int lan   = tid & 63;
  const int lan31 = lan & 31;
  const int g2    = lan >> 5;
  const int w     = tid >> 6;                   // wave id 0..7
  const int kw    = w & 3;                      // key split 0..3
  const int cq    = w >> 2;                     // channel quarter / qh-pair owner: 0/1
  // XCD-aware: batch b pinned to XCDs {2b,2b+1}; decode (q-tile, ch-block)
  const int bid   = blockIdx.x;
  const int xcd   = bid & 7;
  const int b     = xcd >> 1;
  const int inner = bid >> 3;                   // 0..31
  const int cb    = inner & 1;                  // channel block 0/1 (128 ch)
  const int n0    = (((xcd & 1) << 4) | (inner >> 1)) * 128;

  const float gamma = gamma_p[0];

  // query fragments for MY 2 query tiles (qh = cq*2 + qhl): B[k][n]=g[n][k]
  bf16x8 bgM[2][2];
#pragma unroll
  for (int qhl = 0; qhl < 2; ++qhl) {
    const u16* gp = g_ws + ((size_t)b * NSEQ + n0 + (cq * 2 + qhl) * 32 + lan31) * CQK + g2 * 8;
    bgM[qhl][0] = ld8(gp);
    bgM[qhl][1] = ld8(gp + 16);
  }

  f32x16 o[2][4], zfrag;                        // [cg][qh] = 128 acc regs
#pragma unroll
  for (int r = 0; r < 16; ++r) zfrag[r] = 0.f;
#pragma unroll
  for (int cg = 0; cg < 2; ++cg)
#pragma unroll
    for (int qh = 0; qh < 4; ++qh) o[cg][qh] = zfrag;
  float l2[2] = {0.f, 0.f};

  const u16* fbase = f_ws + ((size_t)b * NSEQ + kw * 1024 + lan31) * CQK + g2 * 8;
  const u16* hbase = hT_ws + ((size_t)b * CDIM + cb * 128 + cq * 64 + lan31) * NSEQ
                   + kw * 1024 + g2 * 8;

  bf16x8 af0 = ld8(fbase), af1 = ld8(fbase + 16);
  const u16* fp = fbase + 32 * CQK;

  for (int it = 0; it < 32; ++it) {
    const int p = it & 1;
    // issue f prefetch + this-iter h loads early (land during softmax+barrier)
    bf16x8 naf0 = ld8(fp), naf1 = ld8(fp + 16);
    fp += 32 * CQK;
    const u16* hp = hbase + it * 32;
    bf16x8 ha0 = ld8(hp);
    bf16x8 hb0 = ld8(hp + 16);
    bf16x8 ha1 = ld8(hp + (size_t)32 * NSEQ);
    bf16x8 hb1 = ld8(hp + (size_t)32 * NSEQ + 16);

    // QK + softmax + pack for MY 2 query tiles; write frags to exchange buffer
#pragma unroll
    for (int qhl = 0; qhl < 2; ++qhl) {
      f32x16 s = __builtin_amdgcn_mfma_f32_32x32x16_bf16(af0, bgM[qhl][0], zfrag, 0, 0, 0);
      s        = __builtin_amdgcn_mfma_f32_32x32x16_bf16(af1, bgM[qhl][1], s,     0, 0, 0);

      float pv[16];
#pragma unroll
      for (int r = 0; r < 16; ++r) pv[r] = exp2_raw(s[r]);
      float rs = ((pv[0]+pv[1])+(pv[2]+pv[3])) + ((pv[4]+pv[5])+(pv[6]+pv[7]))
               + ((pv[8]+pv[9])+(pv[10]+pv[11])) + ((pv[12]+pv[13])+(pv[14]+pv[15]));
      auto rr = __builtin_amdgcn_permlane32_swap(__builtin_bit_cast(u32, rs),
                                                 __builtin_bit_cast(u32, rs), false, false);
      l2[qhl] += __builtin_bit_cast(float, (u32)rr[0]) + __builtin_bit_cast(float, (u32)rr[1]);

      u32 q0a = pk2(pv[0],pv[1]),   q0b = pk2(pv[2],pv[3]);
      u32 q1a = pk2(pv[4],pv[5]),   q1b = pk2(pv[6],pv[7]);
      u32 q2a = pk2(pv[8],pv[9]),   q2b = pk2(pv[10],pv[11]);
      u32 q3a = pk2(pv[12],pv[13]), q3b = pk2(pv[14],pv[15]);
      auto r02a = __builtin_amdgcn_permlane32_swap(q0a, q1a, false, false);
      auto r13a = __builtin_amdgcn_permlane32_swap(q0b, q1b, false, false);
      auto r02b = __builtin_amdgcn_permlane32_swap(q2a, q3a, false, false);
      auto r13b = __builtin_amdgcn_permlane32_swap(q2b, q3b, false, false);
      u32x4 u0 = {(u32)r02a[0], (u32)r13a[0], (u32)r02a[1], (u32)r13a[1]};
      u32x4 u1 = {(u32)r02b[0], (u32)r13b[0], (u32)r02b[1], (u32)r13b[1]};
      xb[p][kw][cq * 2 + qhl][0][lan] = u0;
      xb[p][kw][cq * 2 + qhl][1][lan] = u1;
    }

    __syncthreads();                            // frags of all 4 q-tiles visible

    // read all 4 q-tiles' A-frags (uniform, lane-contiguous, conflict-free)
    bf16x8 ap[4][2];
#pragma unroll
    for (int qh = 0; qh < 4; ++qh) {
      ap[qh][0] = __builtin_bit_cast(bf16x8, xb[p][kw][qh][0][lan]);
      ap[qh][1] = __builtin_bit_cast(bf16x8, xb[p][kw][qh][1][lan]);
    }

    // PV: one h load pair feeds 8 MFMAs (4 q-tiles x 2 k-steps)
#pragma unroll
    for (int qh = 0; qh < 4; ++qh) {
      o[0][qh] = __builtin_amdgcn_mfma_f32_32x32x16_bf16(ap[qh][0], ha0, o[0][qh], 0, 0, 0);
      o[0][qh] = __builtin_amdgcn_mfma_f32_32x32x16_bf16(ap[qh][1], hb0, o[0][qh], 0, 0, 0);
      o[1][qh] = __builtin_amdgcn_mfma_f32_32x32x16_bf16(ap[qh][0], ha1, o[1][qh], 0, 0, 0);
      o[1][qh] = __builtin_amdgcn_mfma_f32_32x32x16_bf16(ap[qh][1], hb1, o[1][qh], 0, 0, 0);
    }

    af0 = naf0; af1 = naf1;
  }

  // l partials: each wave owns 2 q-tiles
  lsh[kw][cq * 2 + 0][lan] = l2[0];
  lsh[kw][cq * 2 + 1][lan] = l2[1];

  // ---- combine: 2 rounds (query-tile pairs); 4-way key-split sum via LDS ----
#pragma unroll
  for (int round = 0; round < 2; ++round) {
    __syncthreads();
    {
#pragma unroll
      for (int qhl = 0; qhl < 2; ++qhl)
#pragma unroll
        for (int r = 0; r < 16; ++r)
          pls[kw][cq][qhl][r][lan] = pk2(o[0][round * 2 + qhl][r], o[1][round * 2 + qhl][r]);
    }
    __syncthreads();
    {
      const int qhl = kw & 1, rb = (kw >> 1) * 8;
      const int qh  = round * 2 + qhl;
      float e0[8], e1[8];
#pragma unroll
      for (int j = 0; j < 8; ++j) { e0[j] = 0.f; e1[j] = 0.f; }
#pragma unroll
      for (int kk = 0; kk < 4; ++kk)
#pragma unroll
        for (int j = 0; j < 8; ++j) {
          u32 v = pls[kk][cq][qhl][rb + j][lan];
          e0[j] += __builtin_bit_cast(float, v << 16);
          e1[j] += __builtin_bit_cast(float, v & 0xFFFF0000u);
        }
      const float l_tot = lsh[0][qh][lan] + lsh[1][qh][lan]
                        + lsh[2][qh][lan] + lsh[3][qh][lan];
      const float gi = gamma / l_tot;
#pragma unroll
      for (int j = 0; j < 8; ++j) {
        const int r  = rb + j;
        const int nl = (r & 3) + 8 * (r >> 2) + 4 * g2;   // query row within 32-tile
        const float gir = __shfl(gi, nl);
        const size_t row = (size_t)b * NSEQ + n0 + qh * 32 + nl;
        const size_t i0 = row * CDIM + cb * 128 + cq * 64 + lan31;
        out[i0]      = fmaf(gir, e0[j], x[i0]);
        out[i0 + 32] = fmaf(gir, e1[j], x[i0 + 32]);
      }
    }
  }
}

extern "C" void kernel_launch(void* const* d_in, const int* in_sizes, int n_in,
                              void* d_out, int out_size, void* d_ws, size_t ws_size,
                              hipStream_t stream) {
  const float* x     = (const float*)d_in[0];
  const float* Wf    = (const float*)d_in[1];
  const float* bf    = (const float*)d_in[2];
  const float* Wg    = (const float*)d_in[3];
  const float* bg    = (const float*)d_in[4];
  const float* Wh    = (const float*)d_in[5];
  const float* bh    = (const float*)d_in[6];
  const float* gamma = (const float*)d_in[7];
  float* out = (float*)d_out;

  // layout: hT first so prefetch overruns land in f/g (in-bounds)
  u16* hT_ws = (u16*)d_ws;                                   // 8 MB
  u16* f_ws  = hT_ws + (size_t)BATCH * CDIM * NSEQ;          // 1 MB
  u16* g_ws  = f_ws  + (size_t)BATCH * NSEQ * CQK;           // 1 MB

  hipLaunchKernelGGL(proj_kernel, dim3(1024), dim3(256), 0, stream,
                     x, Wf, bf, Wg, bg, Wh, bh, f_ws, g_ws, hT_ws);
  hipLaunchKernelGGL(attn_kernel, dim3(256), dim3(512), 0, stream,
                     x, gamma, f_ws, g_ws, hT_ws, out);
}

// Round 15
// 86.331 us; speedup vs baseline: 2.2390x; 1.3821x over previous
//
#include <hip/hip_runtime.h>
#include <hip/hip_bf16.h>

#define BATCH 4
#define NSEQ  4096
#define CDIM  256
#define CQK   32
#define L2E   1.44269504088896340736f

typedef short bf16x8 __attribute__((ext_vector_type(8)));   // 8 bf16 in 4 VGPRs
typedef float f32x16 __attribute__((ext_vector_type(16)));
typedef unsigned short u16;
typedef unsigned int   u32;
typedef unsigned int   u32x4 __attribute__((ext_vector_type(4)));

__device__ __forceinline__ u32 pk2(float lo, float hi) {    // v_cvt_pk_bf16_f32
  u16 a = __builtin_bit_cast(u16, __float2bfloat16(lo));
  u16 b = __builtin_bit_cast(u16, __float2bfloat16(hi));
  return (u32)a | ((u32)b << 16);
}
__device__ __forceinline__ bf16x8 ld8(const u16* p) {
  uint4 u = *(const uint4*)p;
  return __builtin_bit_cast(bf16x8, u);
}
// raw v_exp_f32 via builtin (hazard-safe; inline-asm version failed r9 at absmax 2.69)
__device__ __forceinline__ float exp2_raw(float x) {
#if __has_builtin(__builtin_amdgcn_exp2f)
  return __builtin_amdgcn_exp2f(x);
#else
  return exp2f(x);
#endif
}

// ---------------- weight prep: W[k][c] (f32) -> WT[c][k] (bf16); WfT pre-scaled by L2E --
__global__ __launch_bounds__(64) void prep_kernel(
    const float* __restrict__ Wf, const float* __restrict__ Wg, const float* __restrict__ Wh,
    u16* __restrict__ wfT, u16* __restrict__ wgT, u16* __restrict__ whT) {
  const int cb = blockIdx.x, t = threadIdx.x;
#pragma unroll
  for (int j = 0; j < 4; ++j) {
    const int k = t + j * 64;
    if (cb < 32) {
      wfT[cb * 256 + k] = (u16)(pk2(Wf[k * CQK + cb] * L2E, 0.f) & 0xFFFF);
    } else if (cb < 64) {
      const int c = cb - 32;
      wgT[c * 256 + k] = (u16)(pk2(Wg[k * CQK + c], 0.f) & 0xFFFF);
    } else {
      const int c = cb - 64;
      whT[c * 256 + k] = (u16)(pk2(Wh[k * CDIM + c], 0.f) & 0xFFFF);
    }
  }
}

// ---------------- MFMA projection: f,g (bf16 [B*N][32]) and hT (bf16 [B][256][4096]) ----
// Block = 4 waves; wave (w&1) = 32-row strip, (w>>1) = channel half. One x-fragment set
// serves as A for f/g (D[row][c]) and as B for hT (D[c][row], swapped operands).
// mfma_f32_32x32x16_bf16: A[row=l&31][k=(l>>5)*8+i], B[k=(l>>5)*8+i][col=l&31],
//   D[row=(r&3)+8*(r>>2)+4*(l>>5)][col=l&31]
__global__ __launch_bounds__(256, 1) void proj_kernel(
    const float* __restrict__ x,
    const float* __restrict__ bfv, const float* __restrict__ bgv, const float* __restrict__ bhv,
    const u16* __restrict__ wfT, const u16* __restrict__ wgT, const u16* __restrict__ whT,
    u16* __restrict__ f_ws, u16* __restrict__ g_ws, u16* __restrict__ hT_ws) {
  const int tid   = threadIdx.x;
  const int lan   = tid & 63;
  const int lan31 = lan & 31;
  const int g2    = lan >> 5;
  const int w     = tid >> 6;
  const int half  = w >> 1;                     // channel half 0/1
  const int row0  = blockIdx.x * 64 + (w & 1) * 32;
  const int b     = row0 >> 12, n0 = row0 & (NSEQ - 1);

  // x fragments: xf[ks] = x[row0+lan31][ks*16 + g2*8 .. +8], f32 -> bf16
  bf16x8 xf[16];
  const float* xr = x + ((size_t)row0 + lan31) * CDIM + g2 * 8;
#pragma unroll
  for (int ks = 0; ks < 16; ++ks) {
    float4 a = *(const float4*)(xr + ks * 16);
    float4 c = *(const float4*)(xr + ks * 16 + 4);
    u32x4 u = { pk2(a.x, a.y), pk2(a.z, a.w), pk2(c.x, c.y), pk2(c.z, c.w) };
    xf[ks] = __builtin_bit_cast(bf16x8, u);
  }

  { // f (half 0) or g (half 1): D[m=row][n=c]
    const u16*  wT   = half ? wgT : wfT;
    const float bias = half ? bgv[lan31] : bfv[lan31] * L2E;
    f32x16 acc;
#pragma unroll
    for (int r = 0; r < 16; ++r) acc[r] = bias;
    const u16* wp = wT + lan31 * 256 + g2 * 8;
#pragma unroll
    for (int ks = 0; ks < 16; ++ks)
      acc = __builtin_amdgcn_mfma_f32_32x32x16_bf16(xf[ks], ld8(wp + ks * 16), acc, 0, 0, 0);
    u16* dst = half ? g_ws : f_ws;
#pragma unroll
    for (int r = 0; r < 16; ++r) {
      const int row = (r & 3) + 8 * (r >> 2) + 4 * g2;
      dst[((size_t)row0 + row) * CQK + lan31] = (u16)(pk2(acc[r], 0.f) & 0xFFFF);
    }
  }

  // h: 4 channel tiles of 32; D[m=c][n=row] via swapped operands -> hT directly
#pragma unroll
  for (int t = 0; t < 4; ++t) {
    const int ct = half * 128 + t * 32;
    f32x16 acc;
#pragma unroll
    for (int r = 0; r < 16; ++r)
      acc[r] = bhv[ct + (r & 3) + 8 * (r >> 2) + 4 * g2];
    const u16* wp = whT + (size_t)(ct + lan31) * 256 + g2 * 8;
#pragma unroll
    for (int ks = 0; ks < 16; ++ks)
      acc = __builtin_amdgcn_mfma_f32_32x32x16_bf16(ld8(wp + ks * 16), xf[ks], acc, 0, 0, 0);
#pragma unroll
    for (int r = 0; r < 16; ++r) {
      const int c = ct + (r & 3) + 8 * (r >> 2) + 4 * g2;
      hT_ws[((size_t)b * CDIM + c) * NSEQ + n0 + lan31] = (u16)(pk2(acc[r], 0.f) & 0xFFFF);
    }
  }
}

// ---------------- flash attention: 128q tiles, LDS P-exchange (unchanged from r14) ------
__global__ __launch_bounds__(512, 2) void attn_kernel(
    const float* __restrict__ x, const float* __restrict__ gamma_p,
    const u16* __restrict__ f_ws, const u16* __restrict__ g_ws,
    const u16* __restrict__ hT_ws, float* __restrict__ out) {
  __shared__ u32x4 xb[2][4][4][2][64];          // [buf][kw][qh][fr][lane] 64KB P-exchange
  __shared__ u32   pls[4][2][2][16][64];        // [kw][cq][qhl][r][lane] 64KB combine
  __shared__ float lsh[4][4][64];               // [kw][qh][lane] 4KB

  const int tid   = threadIdx.x;
  const int lan   = tid & 63;
  const int lan31 = lan & 31;
  const int g2    = lan >> 5;
  const int w     = tid >> 6;                   // wave id 0..7
  const int kw    = w & 3;                      // key split 0..3
  const int cq    = w >> 2;                     // channel quarter / qh-pair owner: 0/1
  const int bid   = blockIdx.x;
  const int xcd   = bid & 7;
  const int b     = xcd >> 1;
  const int inner = bid >> 3;                   // 0..31
  const int cb    = inner & 1;                  // channel block 0/1 (128 ch)
  const int n0    = (((xcd & 1) << 4) | (inner >> 1)) * 128;

  const float gamma = gamma_p[0];

  bf16x8 bgM[2][2];
#pragma unroll
  for (int qhl = 0; qhl < 2; ++qhl) {
    const u16* gp = g_ws + ((size_t)b * NSEQ + n0 + (cq * 2 + qhl) * 32 + lan31) * CQK + g2 * 8;
    bgM[qhl][0] = ld8(gp);
    bgM[qhl][1] = ld8(gp + 16);
  }

  f32x16 o[2][4], zfrag;
#pragma unroll
  for (int r = 0; r < 16; ++r) zfrag[r] = 0.f;
#pragma unroll
  for (int cg = 0; cg < 2; ++cg)
#pragma unroll
    for (int qh = 0; qh < 4; ++qh) o[cg][qh] = zfrag;
  float l2[2] = {0.f, 0.f};

  const u16* fbase = f_ws + ((size_t)b * NSEQ + kw * 1024 + lan31) * CQK + g2 * 8;
  const u16* hbase = hT_ws + ((size_t)b * CDIM + cb * 128 + cq * 64 + lan31) * NSEQ
                   + kw * 1024 + g2 * 8;

  bf16x8 af0 = ld8(fbase), af1 = ld8(fbase + 16);
  const u16* fp = fbase + 32 * CQK;

  for (int it = 0; it < 32; ++it) {
    const int p = it & 1;
    bf16x8 naf0 = ld8(fp), naf1 = ld8(fp + 16);
    fp += 32 * CQK;
    const u16* hp = hbase + it * 32;
    bf16x8 ha0 = ld8(hp);
    bf16x8 hb0 = ld8(hp + 16);
    bf16x8 ha1 = ld8(hp + (size_t)32 * NSEQ);
    bf16x8 hb1 = ld8(hp + (size_t)32 * NSEQ + 16);

#pragma unroll
    for (int qhl = 0; qhl < 2; ++qhl) {
      f32x16 s = __builtin_amdgcn_mfma_f32_32x32x16_bf16(af0, bgM[qhl][0], zfrag, 0, 0, 0);
      s        = __builtin_amdgcn_mfma_f32_32x32x16_bf16(af1, bgM[qhl][1], s,     0, 0, 0);

      float pv[16];
#pragma unroll
      for (int r = 0; r < 16; ++r) pv[r] = exp2_raw(s[r]);
      float rs = ((pv[0]+pv[1])+(pv[2]+pv[3])) + ((pv[4]+pv[5])+(pv[6]+pv[7]))
               + ((pv[8]+pv[9])+(pv[10]+pv[11])) + ((pv[12]+pv[13])+(pv[14]+pv[15]));
      auto rr = __builtin_amdgcn_permlane32_swap(__builtin_bit_cast(u32, rs),
                                                 __builtin_bit_cast(u32, rs), false, false);
      l2[qhl] += __builtin_bit_cast(float, (u32)rr[0]) + __builtin_bit_cast(float, (u32)rr[1]);

      u32 q0a = pk2(pv[0],pv[1]),   q0b = pk2(pv[2],pv[3]);
      u32 q1a = pk2(pv[4],pv[5]),   q1b = pk2(pv[6],pv[7]);
      u32 q2a = pk2(pv[8],pv[9]),   q2b = pk2(pv[10],pv[11]);
      u32 q3a = pk2(pv[12],pv[13]), q3b = pk2(pv[14],pv[15]);
      auto r02a = __builtin_amdgcn_permlane32_swap(q0a, q1a, false, false);
      auto r13a = __builtin_amdgcn_permlane32_swap(q0b, q1b, false, false);
      auto r02b = __builtin_amdgcn_permlane32_swap(q2a, q3a, false, false);
      auto r13b = __builtin_amdgcn_permlane32_swap(q2b, q3b, false, false);
      u32x4 u0 = {(u32)r02a[0], (u32)r13a[0], (u32)r02a[1], (u32)r13a[1]};
      u32x4 u1 = {(u32)r02b[0], (u32)r13b[0], (u32)r02b[1], (u32)r13b[1]};
      xb[p][kw][cq * 2 + qhl][0][lan] = u0;
      xb[p][kw][cq * 2 + qhl][1][lan] = u1;
    }

    __syncthreads();

    bf16x8 ap[4][2];
#pragma unroll
    for (int qh = 0; qh < 4; ++qh) {
      ap[qh][0] = __builtin_bit_cast(bf16x8, xb[p][kw][qh][0][lan]);
      ap[qh][1] = __builtin_bit_cast(bf16x8, xb[p][kw][qh][1][lan]);
    }

#pragma unroll
    for (int qh = 0; qh < 4; ++qh) {
      o[0][qh] = __builtin_amdgcn_mfma_f32_32x32x16_bf16(ap[qh][0], ha0, o[0][qh], 0, 0, 0);
      o[0][qh] = __builtin_amdgcn_mfma_f32_32x32x16_bf16(ap[qh][1], hb0, o[0][qh], 0, 0, 0);
      o[1][qh] = __builtin_amdgcn_mfma_f32_32x32x16_bf16(ap[qh][0], ha1, o[1][qh], 0, 0, 0);
      o[1][qh] = __builtin_amdgcn_mfma_f32_32x32x16_bf16(ap[qh][1], hb1, o[1][qh], 0, 0, 0);
    }

    af0 = naf0; af1 = naf1;
  }

  lsh[kw][cq * 2 + 0][lan] = l2[0];
  lsh[kw][cq * 2 + 1][lan] = l2[1];

#pragma unroll
  for (int round = 0; round < 2; ++round) {
    __syncthreads();
    {
#pragma unroll
      for (int qhl = 0; qhl < 2; ++qhl)
#pragma unroll
        for (int r = 0; r < 16; ++r)
          pls[kw][cq][qhl][r][lan] = pk2(o[0][round * 2 + qhl][r], o[1][round * 2 + qhl][r]);
    }
    __syncthreads();
    {
      const int qhl = kw & 1, rb = (kw >> 1) * 8;
      const int qh  = round * 2 + qhl;
      float e0[8], e1[8];
#pragma unroll
      for (int j = 0; j < 8; ++j) { e0[j] = 0.f; e1[j] = 0.f; }
#pragma unroll
      for (int kk = 0; kk < 4; ++kk)
#pragma unroll
        for (int j = 0; j < 8; ++j) {
          u32 v = pls[kk][cq][qhl][rb + j][lan];
          e0[j] += __builtin_bit_cast(float, v << 16);
          e1[j] += __builtin_bit_cast(float, v & 0xFFFF0000u);
        }
      const float l_tot = lsh[0][qh][lan] + lsh[1][qh][lan]
                        + lsh[2][qh][lan] + lsh[3][qh][lan];
      const float gi = gamma / l_tot;
#pragma unroll
      for (int j = 0; j < 8; ++j) {
        const int r  = rb + j;
        const int nl = (r & 3) + 8 * (r >> 2) + 4 * g2;
        const float gir = __shfl(gi, nl);
        const size_t row = (size_t)b * NSEQ + n0 + qh * 32 + nl;
        const size_t i0 = row * CDIM + cb * 128 + cq * 64 + lan31;
        out[i0]      = fmaf(gir, e0[j], x[i0]);
        out[i0 + 32] = fmaf(gir, e1[j], x[i0 + 32]);
      }
    }
  }
}

extern "C" void kernel_launch(void* const* d_in, const int* in_sizes, int n_in,
                              void* d_out, int out_size, void* d_ws, size_t ws_size,
                              hipStream_t stream) {
  const float* x     = (const float*)d_in[0];
  const float* Wf    = (const float*)d_in[1];
  const float* bf    = (const float*)d_in[2];
  const float* Wg    = (const float*)d_in[3];
  const float* bg    = (const float*)d_in[4];
  const float* Wh    = (const float*)d_in[5];
  const float* bh    = (const float*)d_in[6];
  const float* gamma = (const float*)d_in[7];
  float* out = (float*)d_out;

  // layout: hT | f | g | wfT | wgT | whT  (hT first so f-prefetch overruns land in f/g)
  u16* hT_ws = (u16*)d_ws;                                   // 8 MB
  u16* f_ws  = hT_ws + (size_t)BATCH * CDIM * NSEQ;          // 1 MB
  u16* g_ws  = f_ws  + (size_t)BATCH * NSEQ * CQK;           // 1 MB
  u16* wfT   = g_ws  + (size_t)BATCH * NSEQ * CQK;           // 16 KB
  u16* wgT   = wfT   + (size_t)CQK * CDIM;                   // 16 KB
  u16* whT   = wgT   + (size_t)CQK * CDIM;                   // 128 KB

  hipLaunchKernelGGL(prep_kernel, dim3(320), dim3(64), 0, stream,
                     Wf, Wg, Wh, wfT, wgT, whT);
  hipLaunchKernelGGL(proj_kernel, dim3(256), dim3(256), 0, stream,
                     x, bf, bg, bh, wfT, wgT, whT, f_ws, g_ws, hT_ws);
  hipLaunchKernelGGL(attn_kernel, dim3(256), dim3(512), 0, stream,
                     x, gamma, f_ws, g_ws, hT_ws, out);
}

// Round 17
// 82.301 us; speedup vs baseline: 2.3487x; 1.0490x over previous
//
#include <hip/hip_runtime.h>
#include <hip/hip_bf16.h>

#define BATCH 4
#define NSEQ  4096
#define CDIM  256
#define CQK   32
#define L2E   1.44269504088896340736f

typedef short bf16x8 __attribute__((ext_vector_type(8)));   // 8 bf16 in 4 VGPRs
typedef float f32x16 __attribute__((ext_vector_type(16)));
typedef unsigned short u16;
typedef unsigned int   u32;
typedef unsigned int   u32x4 __attribute__((ext_vector_type(4)));

__device__ __forceinline__ u32 pk2(float lo, float hi) {    // v_cvt_pk_bf16_f32
  u16 a = __builtin_bit_cast(u16, __float2bfloat16(lo));
  u16 b = __builtin_bit_cast(u16, __float2bfloat16(hi));
  return (u32)a | ((u32)b << 16);
}
__device__ __forceinline__ bf16x8 ld8(const u16* p) {
  uint4 u = *(const uint4*)p;
  return __builtin_bit_cast(bf16x8, u);
}
// raw v_exp_f32 via builtin (hazard-safe; inline-asm version failed r9 at absmax 2.69)
__device__ __forceinline__ float exp2_raw(float x) {
#if __has_builtin(__builtin_amdgcn_exp2f)
  return __builtin_amdgcn_exp2f(x);
#else
  return exp2f(x);
#endif
}

// ---------------- weight prep: W[k][c] (f32) -> WT[c][k] (bf16); WfT pre-scaled by L2E --
__global__ __launch_bounds__(64) void prep_kernel(
    const float* __restrict__ Wf, const float* __restrict__ Wg, const float* __restrict__ Wh,
    u16* __restrict__ wfT, u16* __restrict__ wgT, u16* __restrict__ whT) {
  const int cb = blockIdx.x, t = threadIdx.x;
#pragma unroll
  for (int j = 0; j < 4; ++j) {
    const int k = t + j * 64;
    if (cb < 32) {
      wfT[cb * 256 + k] = (u16)(pk2(Wf[k * CQK + cb] * L2E, 0.f) & 0xFFFF);
    } else if (cb < 64) {
      const int c = cb - 32;
      wgT[c * 256 + k] = (u16)(pk2(Wg[k * CQK + c], 0.f) & 0xFFFF);
    } else {
      const int c = cb - 64;
      whT[c * 256 + k] = (u16)(pk2(Wh[k * CDIM + c], 0.f) & 0xFFFF);
    }
  }
}

// ---------------- MFMA projection -> FRAGMENT-PACKED outputs ----------------------------
// fP[b*128+kc][ks(2)][lane(64)][8]  : A-frag tiles for QK   (kc = 32-key chunk)
// hP[(b*8+cg)*128+kc][ks(2)][lane(64)][8] : B-frag tiles for PV (cg = 32-ch group)
// g stays row-major [B*N][32] (loaded once per attn block).
// Frag maps (verified): A: l'=(key&31)+(((c&15)>>3))*32, j=c&7, ks=c>>4
//                       B: l'=(c&31)+(((key&15)>>3))*32, j=key&7, ks=(key&31)>>4
__global__ __launch_bounds__(256, 1) void proj_kernel(
    const float* __restrict__ x,
    const float* __restrict__ bfv, const float* __restrict__ bgv, const float* __restrict__ bhv,
    const u16* __restrict__ wfT, const u16* __restrict__ wgT, const u16* __restrict__ whT,
    u16* __restrict__ fP, u16* __restrict__ g_ws, u16* __restrict__ hP) {
  const int tid   = threadIdx.x;
  const int lan   = tid & 63;
  const int lan31 = lan & 31;
  const int g2    = lan >> 5;
  const int w     = tid >> 6;
  const int half  = w >> 1;                     // channel half 0/1
  const int row0  = blockIdx.x * 64 + (w & 1) * 32;
  const int b     = row0 >> 12;
  const int kcg   = row0 >> 5;                  // global kc = b*128 + (row0&4095)>>5

  // x fragments: xf[ks] = x[row0+lan31][ks*16 + g2*8 .. +8], f32 -> bf16
  bf16x8 xf[16];
  const float* xr = x + ((size_t)row0 + lan31) * CDIM + g2 * 8;
#pragma unroll
  for (int ks = 0; ks < 16; ++ks) {
    float4 a = *(const float4*)(xr + ks * 16);
    float4 c = *(const float4*)(xr + ks * 16 + 4);
    u32x4 u = { pk2(a.x, a.y), pk2(a.z, a.w), pk2(c.x, c.y), pk2(c.z, c.w) };
    xf[ks] = __builtin_bit_cast(bf16x8, u);
  }

  { // f (half 0, packed) or g (half 1, row-major): D[m=row(key)][n=c]
    const u16*  wT   = half ? wgT : wfT;
    const float bias = half ? bgv[lan31] : bfv[lan31] * L2E;
    f32x16 acc;
#pragma unroll
    for (int r = 0; r < 16; ++r) acc[r] = bias;
    const u16* wp = wT + lan31 * 256 + g2 * 8;
#pragma unroll
    for (int ks = 0; ks < 16; ++ks)
      acc = __builtin_amdgcn_mfma_f32_32x32x16_bf16(xf[ks], ld8(wp + ks * 16), acc, 0, 0, 0);
    if (half) {
#pragma unroll
      for (int r = 0; r < 16; ++r) {
        const int row = (r & 3) + 8 * (r >> 2) + 4 * g2;
        g_ws[((size_t)row0 + row) * CQK + lan31] = (u16)(pk2(acc[r], 0.f) & 0xFFFF);
      }
    } else {
      u16* fb = fP + (size_t)kcg * 1024
              + (lan31 >> 4) * 512 + ((lan31 >> 3) & 1) * 256 + (lan31 & 7);
#pragma unroll
      for (int r = 0; r < 16; ++r) {
        const int crow = (r & 3) + 8 * (r >> 2) + 4 * g2;   // key row within chunk
        fb[crow * 8] = (u16)(pk2(acc[r], 0.f) & 0xFFFF);
      }
    }
  }

  // h: 4 channel tiles of 32; D[m=c][n=row(key)] via swapped operands -> packed B-frags
#pragma unroll
  for (int t = 0; t < 4; ++t) {
    const int ct = half * 128 + t * 32;
    f32x16 acc;
#pragma unroll
    for (int r = 0; r < 16; ++r)
      acc[r] = bhv[ct + (r & 3) + 8 * (r >> 2) + 4 * g2];
    const u16* wp = whT + (size_t)(ct + lan31) * 256 + g2 * 8;
#pragma unroll
    for (int ks = 0; ks < 16; ++ks)
      acc = __builtin_amdgcn_mfma_f32_32x32x16_bf16(ld8(wp + ks * 16), xf[ks], acc, 0, 0, 0);
    const int cg = half * 4 + t;
    u16* hb = hP + ((size_t)(b * 8 + cg) * 128 + ((row0 & (NSEQ - 1)) >> 5)) * 1024
            + (lan31 >> 4) * 512 + ((lan31 >> 3) & 1) * 256 + (lan31 & 7);
#pragma unroll
    for (int r = 0; r < 16; ++r) {
      const int crow = (r & 3) + 8 * (r >> 2) + 4 * g2;     // channel row within group
      hb[crow * 8] = (u16)(pk2(acc[r], 0.f) & 0xFFFF);
    }
  }
}

// ---------------- flash attention: 128q tiles, P-exchange, COALESCED packed loads -------
__global__ __launch_bounds__(512, 2) void attn_kernel(
    const float* __restrict__ x, const float* __restrict__ gamma_p,
    const u16* __restrict__ fP, const u16* __restrict__ g_ws,
    const u16* __restrict__ hP, float* __restrict__ out) {
  __shared__ u32x4 xb[2][4][4][2][64];          // [buf][kw][qh][fr][lane] 64KB P-exchange
  __shared__ u32   pls[4][2][2][16][64];        // [kw][cq][qhl][r][lane] 64KB combine
  __shared__ float lsh[4][4][64];               // [kw][qh][lane] 4KB

  const int tid   = threadIdx.x;
  const int lan   = tid & 63;
  const int lan31 = lan & 31;
  const int g2    = lan >> 5;
  const int w     = tid >> 6;                   // wave id 0..7
  const int kw    = w & 3;                      // key split 0..3
  const int cq    = w >> 2;                     // channel quarter / qh-pair owner: 0/1
  const int bid   = blockIdx.x;
  const int xcd   = bid & 7;
  const int b     = xcd >> 1;
  const int inner = bid >> 3;                   // 0..31
  const int cb    = inner & 1;                  // channel block 0/1 (128 ch)
  const int n0    = (((xcd & 1) << 4) | (inner >> 1)) * 128;

  const float gamma = gamma_p[0];

  bf16x8 bgM[2][2];
#pragma unroll
  for (int qhl = 0; qhl < 2; ++qhl) {
    const u16* gp = g_ws + ((size_t)b * NSEQ + n0 + (cq * 2 + qhl) * 32 + lan31) * CQK + g2 * 8;
    bgM[qhl][0] = ld8(gp);
    bgM[qhl][1] = ld8(gp + 16);
  }

  f32x16 o[2][4], zfrag;
#pragma unroll
  for (int r = 0; r < 16; ++r) zfrag[r] = 0.f;
#pragma unroll
  for (int cg = 0; cg < 2; ++cg)
#pragma unroll
    for (int qh = 0; qh < 4; ++qh) o[cg][qh] = zfrag;
  float l2[2] = {0.f, 0.f};

  // coalesced packed pointers: lane i reads base + i*16B; per-iter stride 2KB
  const u16* fpk  = fP + (size_t)(b * 128 + kw * 32) * 1024 + lan * 8;
  const u16* hpk0 = hP + ((size_t)(b * 8 + cb * 4 + cq * 2) * 128 + kw * 32) * 1024 + lan * 8;
  const u16* hpk1 = hpk0 + (size_t)128 * 1024;

  bf16x8 af0 = ld8(fpk), af1 = ld8(fpk + 512);
  fpk += 1024;

  for (int it = 0; it < 32; ++it) {
    const int p = it & 1;
    bf16x8 naf0 = ld8(fpk), naf1 = ld8(fpk + 512);          // f prefetch (overrun -> g_ws)
    fpk += 1024;
    bf16x8 ha0 = ld8(hpk0), hb0 = ld8(hpk0 + 512);
    bf16x8 ha1 = ld8(hpk1), hb1 = ld8(hpk1 + 512);
    hpk0 += 1024; hpk1 += 1024;

#pragma unroll
    for (int qhl = 0; qhl < 2; ++qhl) {
      f32x16 s = __builtin_amdgcn_mfma_f32_32x32x16_bf16(af0, bgM[qhl][0], zfrag, 0, 0, 0);
      s        = __builtin_amdgcn_mfma_f32_32x32x16_bf16(af1, bgM[qhl][1], s,     0, 0, 0);

      float pv[16];
#pragma unroll
      for (int r = 0; r < 16; ++r) pv[r] = exp2_raw(s[r]);
      float rs = ((pv[0]+pv[1])+(pv[2]+pv[3])) + ((pv[4]+pv[5])+(pv[6]+pv[7]))
               + ((pv[8]+pv[9])+(pv[10]+pv[11])) + ((pv[12]+pv[13])+(pv[14]+pv[15]));
      auto rr = __builtin_amdgcn_permlane32_swap(__builtin_bit_cast(u32, rs),
                                                 __builtin_bit_cast(u32, rs), false, false);
      l2[qhl] += __builtin_bit_cast(float, (u32)rr[0]) + __builtin_bit_cast(float, (u32)rr[1]);

      u32 q0a = pk2(pv[0],pv[1]),   q0b = pk2(pv[2],pv[3]);
      u32 q1a = pk2(pv[4],pv[5]),   q1b = pk2(pv[6],pv[7]);
      u32 q2a = pk2(pv[8],pv[9]),   q2b = pk2(pv[10],pv[11]);
      u32 q3a = pk2(pv[12],pv[13]), q3b = pk2(pv[14],pv[15]);
      auto r02a = __builtin_amdgcn_permlane32_swap(q0a, q1a, false, false);
      auto r13a = __builtin_amdgcn_permlane32_swap(q0b, q1b, false, false);
      auto r02b = __builtin_amdgcn_permlane32_swap(q2a, q3a, false, false);
      auto r13b = __builtin_amdgcn_permlane32_swap(q2b, q3b, false, false);
      u32x4 u0 = {(u32)r02a[0], (u32)r13a[0], (u32)r02a[1], (u32)r13a[1]};
      u32x4 u1 = {(u32)r02b[0], (u32)r13b[0], (u32)r02b[1], (u32)r13b[1]};
      xb[p][kw][cq * 2 + qhl][0][lan] = u0;
      xb[p][kw][cq * 2 + qhl][1][lan] = u1;
    }

    __syncthreads();

    bf16x8 ap[4][2];
#pragma unroll
    for (int qh = 0; qh < 4; ++qh) {
      ap[qh][0] = __builtin_bit_cast(bf16x8, xb[p][kw][qh][0][lan]);
      ap[qh][1] = __builtin_bit_cast(bf16x8, xb[p][kw][qh][1][lan]);
    }

#pragma unroll
    for (int qh = 0; qh < 4; ++qh) {
      o[0][qh] = __builtin_amdgcn_mfma_f32_32x32x16_bf16(ap[qh][0], ha0, o[0][qh], 0, 0, 0);
      o[0][qh] = __builtin_amdgcn_mfma_f32_32x32x16_bf16(ap[qh][1], hb0, o[0][qh], 0, 0, 0);
      o[1][qh] = __builtin_amdgcn_mfma_f32_32x32x16_bf16(ap[qh][0], ha1, o[1][qh], 0, 0, 0);
      o[1][qh] = __builtin_amdgcn_mfma_f32_32x32x16_bf16(ap[qh][1], hb1, o[1][qh], 0, 0, 0);
    }

    af0 = naf0; af1 = naf1;
  }

  lsh[kw][cq * 2 + 0][lan] = l2[0];
  lsh[kw][cq * 2 + 1][lan] = l2[1];

#pragma unroll
  for (int round = 0; round < 2; ++round) {
    __syncthreads();
    {
#pragma unroll
      for (int qhl = 0; qhl < 2; ++qhl)
#pragma unroll
        for (int r = 0; r < 16; ++r)
          pls[kw][cq][qhl][r][lan] = pk2(o[0][round * 2 + qhl][r], o[1][round * 2 + qhl][r]);
    }
    __syncthreads();
    {
      const int qhl = kw & 1, rb = (kw >> 1) * 8;
      const int qh  = round * 2 + qhl;
      float e0[8], e1[8];
#pragma unroll
      for (int j = 0; j < 8; ++j) { e0[j] = 0.f; e1[j] = 0.f; }
#pragma unroll
      for (int kk = 0; kk < 4; ++kk)
#pragma unroll
        for (int j = 0; j < 8; ++j) {
          u32 v = pls[kk][cq][qhl][rb + j][lan];
          e0[j] += __builtin_bit_cast(float, v << 16);
          e1[j] += __builtin_bit_cast(float, v & 0xFFFF0000u);
        }
      const float l_tot = lsh[0][qh][lan] + lsh[1][qh][lan]
                        + lsh[2][qh][lan] + lsh[3][qh][lan];
      const float gi = gamma / l_tot;
#pragma unroll
      for (int j = 0; j < 8; ++j) {
        const int r  = rb + j;
        const int nl = (r & 3) + 8 * (r >> 2) + 4 * g2;
        const float gir = __shfl(gi, nl);
        const size_t row = (size_t)b * NSEQ + n0 + qh * 32 + nl;
        const size_t i0 = row * CDIM + cb * 128 + cq * 64 + lan31;
        out[i0]      = fmaf(gir, e0[j], x[i0]);
        out[i0 + 32] = fmaf(gir, e1[j], x[i0 + 32]);
      }
    }
  }
}

extern "C" void kernel_launch(void* const* d_in, const int* in_sizes, int n_in,
                              void* d_out, int out_size, void* d_ws, size_t ws_size,
                              hipStream_t stream) {
  const float* x     = (const float*)d_in[0];
  const float* Wf    = (const float*)d_in[1];
  const float* bf    = (const float*)d_in[2];
  const float* Wg    = (const float*)d_in[3];
  const float* bg    = (const float*)d_in[4];
  const float* Wh    = (const float*)d_in[5];
  const float* bh    = (const float*)d_in[6];
  const float* gamma = (const float*)d_in[7];
  float* out = (float*)d_out;

  // layout: hP | fP | g | wfT | wgT | whT  (fP before g so f-prefetch overrun lands in g)
  u16* hP   = (u16*)d_ws;                                    // 8 MB
  u16* fPp  = hP  + (size_t)BATCH * CDIM * NSEQ;             // 1 MB
  u16* g_ws = fPp + (size_t)BATCH * NSEQ * CQK;              // 1 MB
  u16* wfT  = g_ws + (size_t)BATCH * NSEQ * CQK;             // 16 KB
  u16* wgT  = wfT + (size_t)CQK * CDIM;                      // 16 KB
  u16* whT  = wgT + (size_t)CQK * CDIM;                      // 128 KB

  hipLaunchKernelGGL(prep_kernel, dim3(320), dim3(64), 0, stream,
                     Wf, Wg, Wh, wfT, wgT, whT);
  hipLaunchKernelGGL(proj_kernel, dim3(256), dim3(256), 0, stream,
                     x, bf, bg, bh, wfT, wgT, whT, fPp, g_ws, hP);
  hipLaunchKernelGGL(attn_kernel, dim3(256), dim3(512), 0, stream,
                     x, gamma, fPp, g_ws, hP, out);
}